// Round 1
// baseline (108.160 us; speedup 1.0000x reference)
//
#include <hip/hip_runtime.h>

#define NF    50000
#define PADP  50001
#define CI    256
#define CO    256
#define KN    9
#define KTOT  2304           // 9*256
#define NCHUNK 782           // ceil(50001/64)

// ---- ws layout (bytes) ----
#define WT_OFF    0u         // 256*2304*2 = 1179648
#define FLAG_OFF  1179904u   // 4
#define CNT_OFF   1180160u   // 782*4
#define SCAN_OFF  1183488u   // 782*4
#define IDX_OFF   1186816u   // 450000*4 = 1800000
#define RANK_OFF  2986816u   // 50001*4 = 200004
#define PADX_OFF  3186944u   // 50001*256*2 = 25600512  (end ~28.8 MB)

typedef float f32x4 __attribute__((ext_vector_type(4)));
typedef __bf16 bf16x8 __attribute__((ext_vector_type(8)));

typedef const __attribute__((address_space(1))) unsigned int* gas_t;
typedef __attribute__((address_space(3))) unsigned int* las_t;

static __device__ __forceinline__ void gll16(const void* g, void* l) {
  __builtin_amdgcn_global_load_lds((gas_t)g, (las_t)l, 16, 0, 0);
}

static __device__ __forceinline__ unsigned short f2bf(float f) {
  unsigned int u = __builtin_bit_cast(unsigned int, f);
  u = u + 0x7fffu + ((u >> 16) & 1u);      // RNE
  return (unsigned short)(u >> 16);
}

// ---------- preprocessing ----------

// Detect whether face_neighborhood is int64 (odd 32-bit words all zero) or int32.
__global__ void k_detect(const unsigned int* __restrict__ raw, int* __restrict__ flag) {
  unsigned int v = raw[threadIdx.x * 2 + 1];
  unsigned long long nz = __ballot(v != 0u);
  if (threadIdx.x == 0) flag[0] = (nz == 0ull) ? 1 : 0;
}

__global__ void k_idx32(const void* __restrict__ raw, const int* __restrict__ flag,
                        int* __restrict__ out, int n) {
  int i = blockIdx.x * blockDim.x + threadIdx.x;
  if (i >= n) return;
  int v;
  if (flag[0]) v = (int)((const long long*)raw)[i];
  else         v = ((const int*)raw)[i];
  out[i] = v;
}

// Demodulate weight and transpose to wt[o][k*256+i] (bf16).
__global__ void k_wt(const float* __restrict__ w, unsigned short* __restrict__ wt) {
  int o = blockIdx.x;
  int i = threadIdx.x;
  const float* wr = w + (o * 256 + i) * 9;
  float wv[9];
  float s = 0.f;
#pragma unroll
  for (int k = 0; k < 9; ++k) { wv[k] = wr[k]; s += wv[k] * wv[k]; }
#pragma unroll
  for (int d = 32; d >= 1; d >>= 1) s += __shfl_xor(s, d);
  __shared__ float red[4];
  if ((i & 63) == 0) red[i >> 6] = s;
  __syncthreads();
  float dc = rsqrtf(red[0] + red[1] + red[2] + red[3] + 1e-8f);
#pragma unroll
  for (int k = 0; k < 9; ++k)
    wt[o * KTOT + k * 256 + i] = f2bf(wv[k] * dc);
}

// Per-64-chunk pad counts.
__global__ void k_cnt(const unsigned char* __restrict__ pad, int* __restrict__ cnt) {
  int t = blockIdx.x * blockDim.x + threadIdx.x;
  bool ip = (t < PADP) ? (pad[t] != 0) : true;
  unsigned long long m = __ballot(ip);
  int c = t >> 6;
  if ((threadIdx.x & 63) == 0 && c < NCHUNK) cnt[c] = __popcll(m);
}

// Exclusive scan of chunk counts (1 wave).
__global__ void k_scan(const int* __restrict__ cnt, int* __restrict__ scan, int n) {
  int lane = threadIdx.x;
  int run = 0;
  for (int base = 0; base < n; base += 64) {
    int i = base + lane;
    int v = (i < n) ? cnt[i] : 0;
    int inc = v;
#pragma unroll
    for (int d = 1; d < 64; d <<= 1) {
      int t = __shfl_up(inc, d);
      if (lane >= d) inc += t;
    }
    if (i < n) scan[i] = run + inc - v;
    run += __shfl(inc, 63);
  }
}

// rank[p] = position among non-pad slots, or -1 for pad rows.
__global__ void k_rank(const unsigned char* __restrict__ pad, const int* __restrict__ scan,
                       int* __restrict__ rank) {
  int p = blockIdx.x * blockDim.x + threadIdx.x;
  bool ip = (p < PADP) ? (pad[p] != 0) : true;
  unsigned long long m = __ballot(ip);
  int lane = threadIdx.x & 63;
  int before = __popcll(m & ((1ull << lane) - 1ull));
  if (p < PADP) rank[p] = ip ? -1 : (p - scan[p >> 6] - before);
}

// padded_x (bf16): padx[p][c] = pad? 0 : x[rank[p]][c]
__global__ void k_padx(const float* __restrict__ x, const int* __restrict__ rank,
                       unsigned short* __restrict__ padx) {
  int wid = threadIdx.x >> 6, lane = threadIdx.x & 63;
  int p = blockIdx.x * 4 + wid;
  if (p >= PADP) return;
  int r = rank[p];
  int c = lane * 4;
  ushort4 ov;
  if (r < 0) { ov.x = 0; ov.y = 0; ov.z = 0; ov.w = 0; }
  else {
    const float4 v = *(const float4*)(x + r * 256 + c);
    ov.x = f2bf(v.x); ov.y = f2bf(v.y); ov.z = f2bf(v.z); ov.w = f2bf(v.w);
  }
  *(ushort4*)(padx + p * 256 + c) = ov;
}

// ---------- main gathered GEMM ----------
// BM=128 faces x BN=256 outs x BK=64, 8 waves (512 thr), each wave 64x64 out.
// LDS: As[128][64] bf16 @0 (16KB), Bs[256][64] bf16 @16384 (32KB).
// Both tiles stored with 16B-slot swizzle: slot s of row r holds global slot s^(r&7).
__global__ __launch_bounds__(512) void k_main(
    const unsigned short* __restrict__ padx,   // [50001][256] bf16
    const unsigned short* __restrict__ wt,     // [256][2304] bf16
    const int* __restrict__ idx,               // [50000][9]
    const float* __restrict__ bias,            // [256]
    float* __restrict__ out) {                 // [50000][256] f32
  __shared__ __align__(16) unsigned char sm[49152];
  const int tid = threadIdx.x;
  const int wid = tid >> 6, lane = tid & 63;
  const int m0 = blockIdx.x * 128;
  const int wm = wid >> 2;   // 0..1 : row half
  const int wn = wid & 3;    // 0..3 : col quarter

  // A staging: 2 gll16 per wave, 8 rows each (8 lanes/row, 16B/lane).
  int sA[2], ldsA[2], iA[2];
#pragma unroll
  for (int j = 0; j < 2; ++j) {
    int r = wid * 16 + j * 8 + (lane >> 3);
    sA[j] = ((lane & 7) ^ (r & 7)) * 8;       // pre-swizzled source slot (elems)
    int f = m0 + r;
    if (f > NF - 1) f = NF - 1;
    iA[j] = f * KN;
    ldsA[j] = (wid * 16 + j * 8) * 128;
  }
  // B staging: 4 gll16 per wave.
  int gB[4], ldsB[4];
#pragma unroll
  for (int j = 0; j < 4; ++j) {
    int o = wid * 32 + j * 8 + (lane >> 3);
    int s = ((lane & 7) ^ (o & 7)) * 8;
    gB[j] = o * KTOT + s;
    ldsB[j] = 16384 + (wid * 32 + j * 8) * 128;
  }

  f32x4 acc[4][4];
#pragma unroll
  for (int a = 0; a < 4; ++a)
#pragma unroll
    for (int b = 0; b < 4; ++b) {
      acc[a][b][0] = 0.f; acc[a][b][1] = 0.f; acc[a][b][2] = 0.f; acc[a][b][3] = 0.f;
    }

  for (int nb = 0; nb < KN; ++nb) {
    const int pA0 = idx[iA[0] + nb] << 8;   // row base in padx (elements)
    const int pA1 = idx[iA[1] + nb] << 8;
#pragma unroll
    for (int c4 = 0; c4 < 4; ++c4) {
      const int ks = nb * 4 + c4;
      const int c0 = c4 * 64;
      // stage A (gathered rows)
      gll16(padx + pA0 + c0 + sA[0], sm + ldsA[0]);
      gll16(padx + pA1 + c0 + sA[1], sm + ldsA[1]);
      // stage B (weight panel)
#pragma unroll
      for (int j = 0; j < 4; ++j)
        gll16(wt + gB[j] + ks * 64, sm + ldsB[j]);
      __syncthreads();
#pragma unroll
      for (int k2 = 0; k2 < 2; ++k2) {
        bf16x8 a[4], b[4];
#pragma unroll
        for (int mi = 0; mi < 4; ++mi) {
          int row = wm * 64 + mi * 16 + (lane & 15);
          int slot = (k2 * 4 + (lane >> 4)) ^ (row & 7);
          a[mi] = *(const bf16x8*)(sm + row * 128 + slot * 16);
        }
#pragma unroll
        for (int ni = 0; ni < 4; ++ni) {
          int o = wn * 64 + ni * 16 + (lane & 15);
          int slot = (k2 * 4 + (lane >> 4)) ^ (o & 7);
          b[ni] = *(const bf16x8*)(sm + 16384 + o * 128 + slot * 16);
        }
#pragma unroll
        for (int mi = 0; mi < 4; ++mi)
#pragma unroll
          for (int ni = 0; ni < 4; ++ni)
            acc[mi][ni] = __builtin_amdgcn_mfma_f32_16x16x32_bf16(
                a[mi], b[ni], acc[mi][ni], 0, 0, 0);
      }
      __syncthreads();
    }
  }

  // epilogue: bias + store (D: col = lane&15, row = (lane>>4)*4 + r)
#pragma unroll
  for (int ni = 0; ni < 4; ++ni) {
    int col = wn * 64 + ni * 16 + (lane & 15);
    float bv = bias[col];
#pragma unroll
    for (int mi = 0; mi < 4; ++mi) {
#pragma unroll
      for (int r = 0; r < 4; ++r) {
        int row = m0 + wm * 64 + mi * 16 + (lane >> 4) * 4 + r;
        if (row < NF) out[row * 256 + col] = acc[mi][ni][r] + bv;
      }
    }
  }
}

extern "C" void kernel_launch(void* const* d_in, const int* in_sizes, int n_in,
                              void* d_out, int out_size, void* d_ws, size_t ws_size,
                              hipStream_t stream) {
  const float* x = (const float*)d_in[0];
  const float* w = (const float*)d_in[1];
  const float* bias = (const float*)d_in[2];
  const void* nbr = d_in[3];
  const unsigned char* pad = (const unsigned char*)d_in[4];
  float* out = (float*)d_out;
  char* ws = (char*)d_ws;

  unsigned short* wt   = (unsigned short*)(ws + WT_OFF);
  int* flag            = (int*)(ws + FLAG_OFF);
  int* cnt             = (int*)(ws + CNT_OFF);
  int* scan            = (int*)(ws + SCAN_OFF);
  int* idx32           = (int*)(ws + IDX_OFF);
  int* rank            = (int*)(ws + RANK_OFF);
  unsigned short* padx = (unsigned short*)(ws + PADX_OFF);

  k_detect<<<1, 64, 0, stream>>>((const unsigned int*)nbr, flag);
  k_idx32<<<(NF * KN + 255) / 256, 256, 0, stream>>>(nbr, flag, idx32, NF * KN);
  k_wt<<<256, 256, 0, stream>>>(w, wt);
  k_cnt<<<196, 256, 0, stream>>>(pad, cnt);
  k_scan<<<1, 64, 0, stream>>>(cnt, scan, NCHUNK);
  k_rank<<<196, 256, 0, stream>>>(pad, scan, rank);
  k_padx<<<(PADP + 3) / 4, 256, 0, stream>>>(x, rank, padx);
  k_main<<<(NF + 127) / 128, 512, 0, stream>>>(padx, wt, idx32, bias, out);
}